// Round 1
// baseline (621.043 us; speedup 1.0000x reference)
//
#include <hip/hip_runtime.h>

#define Bq 8
#define Tq 64
#define Sq 256
#define Hq 768
#define GPB 32          // workgroups per batch
#define NSTEP 64

typedef float f32x4 __attribute__((ext_vector_type(4)));
typedef __bf16 bf16x8 __attribute__((ext_vector_type(8)));

#define TANH_SCALE 2.885390081777927f   // 2*log2(e)
#define LOG2E 1.4426950408889634f

// ---------------- projection GEMMs (bf16 MFMA, direct-from-global frags) -----
// C[r,c] = scale * (sum_k A[r,k] * W[c,k] (+ bias[c]))
__global__ __launch_bounds__(256) void proj_kernel(
    const float* __restrict__ enc, const float* __restrict__ dec,
    const float* __restrict__ Wh, const float* __restrict__ Wd,
    const float* __restrict__ bd,
    float* __restrict__ ef, float* __restrict__ decf)
{
  const int NT = Hq / 64;                       // 12 n-tiles
  int bid = blockIdx.x;
  const int efBlocks = (Bq * Sq / 64) * NT;     // 384
  const float* A; const float* W; float* C; bool hasBias;
  if (bid < efBlocks) { A = enc; W = Wh; C = ef; hasBias = false; }
  else { bid -= efBlocks; A = dec; W = Wd; C = decf; hasBias = true; }
  int bm = bid / NT, bn = bid % NT;
  int w = threadIdx.x >> 6, ln = threadIdx.x & 63;
  int m0 = bm * 64 + (w >> 1) * 32;
  int n0 = bn * 64 + (w & 1) * 32;
  int rsel = ln & 15;
  int kof = (ln >> 4) * 8;
  f32x4 acc[2][2] = {};
  for (int k0 = 0; k0 < Hq; k0 += 32) {
    bf16x8 af[2], bfr[2];
#pragma unroll
    for (int tm = 0; tm < 2; tm++) {
      const float* p = A + (size_t)(m0 + tm * 16 + rsel) * Hq + k0 + kof;
      f32x4 lo = *(const f32x4*)p, hi = *(const f32x4*)(p + 4);
      bf16x8 t;
      t[0] = (__bf16)lo[0]; t[1] = (__bf16)lo[1]; t[2] = (__bf16)lo[2]; t[3] = (__bf16)lo[3];
      t[4] = (__bf16)hi[0]; t[5] = (__bf16)hi[1]; t[6] = (__bf16)hi[2]; t[7] = (__bf16)hi[3];
      af[tm] = t;
    }
#pragma unroll
    for (int tn = 0; tn < 2; tn++) {
      const float* p = W + (size_t)(n0 + tn * 16 + rsel) * Hq + k0 + kof;
      f32x4 lo = *(const f32x4*)p, hi = *(const f32x4*)(p + 4);
      bf16x8 t;
      t[0] = (__bf16)lo[0]; t[1] = (__bf16)lo[1]; t[2] = (__bf16)lo[2]; t[3] = (__bf16)lo[3];
      t[4] = (__bf16)hi[0]; t[5] = (__bf16)hi[1]; t[6] = (__bf16)hi[2]; t[7] = (__bf16)hi[3];
      bfr[tn] = t;
    }
#pragma unroll
    for (int tm = 0; tm < 2; tm++)
#pragma unroll
      for (int tn = 0; tn < 2; tn++)
        acc[tm][tn] = __builtin_amdgcn_mfma_f32_16x16x32_bf16(af[tm], bfr[tn], acc[tm][tn], 0, 0, 0);
  }
  int col = ln & 15, rb = (ln >> 4) * 4;
#pragma unroll
  for (int tm = 0; tm < 2; tm++)
#pragma unroll
    for (int tn = 0; tn < 2; tn++)
#pragma unroll
      for (int j = 0; j < 4; j++) {
        int r = m0 + tm * 16 + rb + j, c = n0 + tn * 16 + col;
        float val = acc[tm][tn][j];
        if (hasBias) val += bd[c];
        C[(size_t)r * Hq + c] = val * TANH_SCALE;
      }
}

// ---------------- persistent scan kernel -------------------------------------
// grid = B*GPB = 256 blocks, 256 threads. Block (b,g) owns rows s = g*8..g*8+7.
// Wave w owns rows s0 = g*8 + 2w, s1 = s0+1. Lane ln owns h = 4ln + 256jj.
__global__ __launch_bounds__(256, 1) void scan_kernel(
    const float* __restrict__ ef, const float* __restrict__ decf,
    const float* __restrict__ enc, const float* __restrict__ emask,
    const float* __restrict__ dmask, const float* __restrict__ cov0,
    const float* __restrict__ vvec, const float* __restrict__ wcvec,
    float* __restrict__ out_ht, float* __restrict__ out_attn,
    float* __restrict__ out_covf,
    float* __restrict__ Zbuf, int* __restrict__ cntbuf,
    float* __restrict__ loss_acc)
{
  __shared__ float lds_hacc[4][Hq];
  __shared__ float zsum[4], lossb[4], zsh;
  const int b = blockIdx.x >> 5;
  const int g = blockIdx.x & 31;
  const int w = threadIdx.x >> 6;
  const int ln = threadIdx.x & 63;
  const int tid = threadIdx.x;
  const int s0 = g * 8 + w * 2, s1 = s0 + 1;
  const int hb = 4 * ln;

  f32x4 vv[3], wcv[3], ef0[3], ef1[3], en0[3], en1[3];
  const float* efr0 = ef + (size_t)(b * Sq + s0) * Hq;
  const float* efr1 = ef + (size_t)(b * Sq + s1) * Hq;
  const float* enr0 = enc + (size_t)(b * Sq + s0) * Hq;
  const float* enr1 = enc + (size_t)(b * Sq + s1) * Hq;
#pragma unroll
  for (int jj = 0; jj < 3; jj++) {
    int o = hb + 256 * jj;
    vv[jj]  = *(const f32x4*)(vvec + o);
    f32x4 wcl = *(const f32x4*)(wcvec + o);
    wcv[jj] = wcl * TANH_SCALE;
    ef0[jj] = *(const f32x4*)(efr0 + o);
    ef1[jj] = *(const f32x4*)(efr1 + o);
    en0[jj] = *(const f32x4*)(enr0 + o);
    en1[jj] = *(const f32x4*)(enr1 + o);
  }
  float cva = cov0[b * Sq + s0], cvb = cov0[b * Sq + s1];
  const float em0 = emask[b * Sq + s0], em1 = emask[b * Sq + s1];

  for (int t = 0; t < NSTEP; t++) {
    const float* dr = decf + (size_t)(b * Tq + t) * Hq;
    f32x4 dv[3];
#pragma unroll
    for (int jj = 0; jj < 3; jj++) dv[jj] = *(const f32x4*)(dr + hb + 256 * jj);

    float acc0 = 0.f, acc1 = 0.f;
#pragma unroll
    for (int jj = 0; jj < 3; jj++)
#pragma unroll
      for (int e = 0; e < 4; e++) {
        float d = dv[jj][e], wcx = wcv[jj][e], vx = vv[jj][e];
        float xa = ef0[jj][e] + d + cva * wcx;    // already scaled by 2*log2(e)
        float xb = ef1[jj][e] + d + cvb * wcx;
        float ta = 1.f - 2.f * __builtin_amdgcn_rcpf(1.f + __builtin_amdgcn_exp2f(xa));
        float tb = 1.f - 2.f * __builtin_amdgcn_rcpf(1.f + __builtin_amdgcn_exp2f(xb));
        acc0 += vx * ta;
        acc1 += vx * tb;
      }
#pragma unroll
    for (int off = 32; off; off >>= 1) {
      acc0 += __shfl_xor(acc0, off);
      acc1 += __shfl_xor(acc1, off);
    }
    float E0 = __builtin_amdgcn_exp2f(acc0 * LOG2E) * em0;
    float E1 = __builtin_amdgcn_exp2f(acc1 * LOG2E) * em1;
    if (ln == 0) zsum[w] = E0 + E1;
    // unnormalized ht partial for this wave's 2 rows (overlaps the Z wait)
#pragma unroll
    for (int jj = 0; jj < 3; jj++) {
      f32x4 hv = en0[jj] * E0 + en1[jj] * E1;
      *(f32x4*)&lds_hacc[w][hb + 256 * jj] = hv;
    }
    __syncthreads();
    const int slot = b * NSTEP + t;
    if (tid == 0) {
      float zp = zsum[0] + zsum[1] + zsum[2] + zsum[3];
      atomicAdd(&Zbuf[slot], zp);
      __threadfence();
      atomicAdd(&cntbuf[slot], 1);
      while (__hip_atomic_load(&cntbuf[slot], __ATOMIC_ACQUIRE, __HIP_MEMORY_SCOPE_AGENT) < GPB) {}
      zsh = __hip_atomic_load(&Zbuf[slot], __ATOMIC_RELAXED, __HIP_MEMORY_SCOPE_AGENT);
    }
    __syncthreads();
    const float invZ = __builtin_amdgcn_rcpf(zsh);
    float at0 = E0 * invZ, at1 = E1 * invZ;
    float sl = fminf(at0, cva) + fminf(at1, cvb);
    cva += at0; cvb += at1;
    if (ln == 0) {
      out_attn[(size_t)(b * Tq + t) * Sq + s0] = at0;
      out_attn[(size_t)(b * Tq + t) * Sq + s1] = at1;
      lossb[w] = sl;
    }
    float* htp = out_ht + (size_t)(b * Tq + t) * Hq;
#pragma unroll
    for (int jj = 0; jj < 3; jj++) {
      int h = tid + 256 * jj;
      float sum = lds_hacc[0][h] + lds_hacc[1][h] + lds_hacc[2][h] + lds_hacc[3][h];
      atomicAdd(&htp[h], sum * invZ);
    }
    __syncthreads();
    if (tid == 0) {
      float slw = (lossb[0] + lossb[1] + lossb[2] + lossb[3]) * dmask[b * Tq + t];
      atomicAdd(loss_acc, slw);
    }
  }
  if (ln == 0) {
    out_covf[b * Sq + s0] = cva;
    out_covf[b * Sq + s1] = cvb;
  }
}

// ---------------- finalize loss ----------------------------------------------
__global__ __launch_bounds__(256) void finalize_kernel(
    const float* __restrict__ dmask, const float* __restrict__ loss_acc,
    float* __restrict__ out_loss)
{
  __shared__ float red[256];
  float s = 0.f;
  for (int i = threadIdx.x; i < Bq * Tq; i += 256) s += dmask[i];
  red[threadIdx.x] = s;
  __syncthreads();
  if (threadIdx.x == 0) {
    float tot = 0.f;
    for (int i = 0; i < 256; i++) tot += red[i];
    out_loss[0] = loss_acc[0] / tot;
  }
}

extern "C" void kernel_launch(void* const* d_in, const int* in_sizes, int n_in,
                              void* d_out, int out_size, void* d_ws, size_t ws_size,
                              hipStream_t stream) {
  const float* dec   = (const float*)d_in[0];   // [8,64,768]
  const float* dmask = (const float*)d_in[1];   // [8,64]
  const float* enc   = (const float*)d_in[2];   // [8,256,768]
  const float* emask = (const float*)d_in[3];   // [8,256]
  const float* cov0  = (const float*)d_in[4];   // [8,256]
  const float* Wh    = (const float*)d_in[5];   // [768,768]
  const float* Wd    = (const float*)d_in[6];   // [768,768]
  const float* bd    = (const float*)d_in[7];   // [768]
  const float* wc    = (const float*)d_in[8];   // [768]
  const float* vv    = (const float*)d_in[9];   // [768]
  float* out = (float*)d_out;

  char* ws = (char*)d_ws;
  float* ef   = (float*)ws;                         // 2048*768 f32 = 6291456 B
  float* decf = (float*)(ws + 6291456);             // 512*768 f32 = 1572864 B
  float* Zbuf = (float*)(ws + 7864320);             // 512 f32
  int*   cnt  = (int*)  (ws + 7866368);             // 512 i32
  float* lacc = (float*)(ws + 7868416);             // 1 f32

  const size_t OFF_ATTN = (size_t)Bq * Tq * Hq;         // 393216
  const size_t OFF_LOSS = OFF_ATTN + (size_t)Bq * Tq * Sq; // 524288
  const size_t OFF_COV  = OFF_LOSS + 1;                 // 524289

  hipMemsetAsync(d_out, 0, (size_t)out_size * sizeof(float), stream);
  hipMemsetAsync(ws + 7864320, 0, 8192, stream);

  proj_kernel<<<480, 256, 0, stream>>>(enc, dec, Wh, Wd, bd, ef, decf);
  scan_kernel<<<Bq * GPB, 256, 0, stream>>>(ef, decf, enc, emask, dmask, cov0,
                                            vv, wc,
                                            out, out + OFF_ATTN, out + OFF_COV,
                                            Zbuf, cnt, lacc);
  finalize_kernel<<<1, 256, 0, stream>>>(dmask, lacc, out + OFF_LOSS);
}

// Round 2
// 270.316 us; speedup vs baseline: 2.2975x; 2.2975x over previous
//
#include <hip/hip_runtime.h>

#define Bq 8
#define Tq 64
#define Sq 256
#define Hq 768
#define GPB 16          // workgroups per batch (scan)
#define NSTEP 64

typedef float f32x4 __attribute__((ext_vector_type(4)));
typedef __bf16 bf16x8 __attribute__((ext_vector_type(8)));

#define TANH_SCALE 2.885390081777927f   // 2*log2(e)
#define LOG2E 1.4426950408889634f
#define POISON 0xFFFFFFFFu

// ---------------- projection GEMMs (bf16 MFMA, direct-from-global frags) -----
__global__ __launch_bounds__(256) void proj_kernel(
    const float* __restrict__ enc, const float* __restrict__ dec,
    const float* __restrict__ Wh, const float* __restrict__ Wd,
    const float* __restrict__ bd,
    float* __restrict__ ef, float* __restrict__ decf)
{
  const int NT = Hq / 64;                       // 12 n-tiles
  int bid = blockIdx.x;
  const int efBlocks = (Bq * Sq / 64) * NT;     // 384
  const float* A; const float* W; float* C; bool hasBias;
  if (bid < efBlocks) { A = enc; W = Wh; C = ef; hasBias = false; }
  else { bid -= efBlocks; A = dec; W = Wd; C = decf; hasBias = true; }
  int bm = bid / NT, bn = bid % NT;
  int w = threadIdx.x >> 6, ln = threadIdx.x & 63;
  int m0 = bm * 64 + (w >> 1) * 32;
  int n0 = bn * 64 + (w & 1) * 32;
  int rsel = ln & 15;
  int kof = (ln >> 4) * 8;
  f32x4 acc[2][2] = {};
  for (int k0 = 0; k0 < Hq; k0 += 32) {
    bf16x8 af[2], bfr[2];
#pragma unroll
    for (int tm = 0; tm < 2; tm++) {
      const float* p = A + (size_t)(m0 + tm * 16 + rsel) * Hq + k0 + kof;
      f32x4 lo = *(const f32x4*)p, hi = *(const f32x4*)(p + 4);
      bf16x8 t;
      t[0] = (__bf16)lo[0]; t[1] = (__bf16)lo[1]; t[2] = (__bf16)lo[2]; t[3] = (__bf16)lo[3];
      t[4] = (__bf16)hi[0]; t[5] = (__bf16)hi[1]; t[6] = (__bf16)hi[2]; t[7] = (__bf16)hi[3];
      af[tm] = t;
    }
#pragma unroll
    for (int tn = 0; tn < 2; tn++) {
      const float* p = W + (size_t)(n0 + tn * 16 + rsel) * Hq + k0 + kof;
      f32x4 lo = *(const f32x4*)p, hi = *(const f32x4*)(p + 4);
      bf16x8 t;
      t[0] = (__bf16)lo[0]; t[1] = (__bf16)lo[1]; t[2] = (__bf16)lo[2]; t[3] = (__bf16)lo[3];
      t[4] = (__bf16)hi[0]; t[5] = (__bf16)hi[1]; t[6] = (__bf16)hi[2]; t[7] = (__bf16)hi[3];
      bfr[tn] = t;
    }
#pragma unroll
    for (int tm = 0; tm < 2; tm++)
#pragma unroll
      for (int tn = 0; tn < 2; tn++)
        acc[tm][tn] = __builtin_amdgcn_mfma_f32_16x16x32_bf16(af[tm], bfr[tn], acc[tm][tn], 0, 0, 0);
  }
  int col = ln & 15, rb = (ln >> 4) * 4;
#pragma unroll
  for (int tm = 0; tm < 2; tm++)
#pragma unroll
    for (int tn = 0; tn < 2; tn++)
#pragma unroll
      for (int j = 0; j < 4; j++) {
        int r = m0 + tm * 16 + rb + j, c = n0 + tn * 16 + col;
        float val = acc[tm][tn][j];
        if (hasBias) val += bd[c];
        C[(size_t)r * Hq + c] = val * TANH_SCALE;
      }
}

// ---------------- persistent scan kernel -------------------------------------
// 128 blocks x 512 threads. Block (b,g) owns rows s = g*16 .. g*16+15.
// Wave w (of 8) owns rows s0 = g*16 + 2w, s1 = s0+1. Lane ln owns h = 4ln+256jj.
// Per step, only the scalar Z crosses WGs: each WG stores its partial into its
// own slot of Zpart[b][t][g]; every wave polls the 16 slots and reduces.
__global__ __launch_bounds__(512, 1) void scan_kernel(
    const float* __restrict__ ef, const float* __restrict__ decf,
    const float* __restrict__ emask, const float* __restrict__ cov0,
    const float* __restrict__ vvec, const float* __restrict__ wcvec,
    float* __restrict__ out_attn,
    float* __restrict__ Zpart)
{
  __shared__ float zsum[2][8];
  const int b = blockIdx.x >> 4;
  const int g = blockIdx.x & 15;
  const int w = threadIdx.x >> 6;
  const int ln = threadIdx.x & 63;
  const int s0 = g * 16 + w * 2, s1 = s0 + 1;
  const int hb = 4 * ln;

  f32x4 vv[3], wcv[3], ef0[3], ef1[3];
  const float* efr0 = ef + (size_t)(b * Sq + s0) * Hq;
  const float* efr1 = ef + (size_t)(b * Sq + s1) * Hq;
#pragma unroll
  for (int jj = 0; jj < 3; jj++) {
    int o = hb + 256 * jj;
    vv[jj]  = *(const f32x4*)(vvec + o);
    f32x4 wcl = *(const f32x4*)(wcvec + o);
    wcv[jj] = wcl * TANH_SCALE;
    ef0[jj] = *(const f32x4*)(efr0 + o);
    ef1[jj] = *(const f32x4*)(efr1 + o);
  }
  float cva = cov0[b * Sq + s0], cvb = cov0[b * Sq + s1];
  const float em0 = emask[b * Sq + s0], em1 = emask[b * Sq + s1];

  unsigned* Zp = (unsigned*)Zpart;

  // prefetch first decoder row
  f32x4 dv[3];
#pragma unroll
  for (int jj = 0; jj < 3; jj++)
    dv[jj] = *(const f32x4*)(decf + (size_t)(b * Tq) * Hq + hb + 256 * jj);

  for (int t = 0; t < NSTEP; t++) {
    const int par = t & 1;
    float acc0 = 0.f, acc1 = 0.f;
#pragma unroll
    for (int jj = 0; jj < 3; jj++)
#pragma unroll
      for (int e = 0; e < 4; e++) {
        float d = dv[jj][e], wcx = wcv[jj][e], vx = vv[jj][e];
        float xa = ef0[jj][e] + d + cva * wcx;    // pre-scaled by 2*log2(e)
        float xb = ef1[jj][e] + d + cvb * wcx;
        float ta = 1.f - 2.f * __builtin_amdgcn_rcpf(1.f + __builtin_amdgcn_exp2f(xa));
        float tb = 1.f - 2.f * __builtin_amdgcn_rcpf(1.f + __builtin_amdgcn_exp2f(xb));
        acc0 += vx * ta;
        acc1 += vx * tb;
      }
#pragma unroll
    for (int off = 32; off; off >>= 1) {
      acc0 += __shfl_xor(acc0, off);
      acc1 += __shfl_xor(acc1, off);
    }
    float E0 = __builtin_amdgcn_exp2f(acc0 * LOG2E) * em0;
    float E1 = __builtin_amdgcn_exp2f(acc1 * LOG2E) * em1;
    if (ln == 0) zsum[par][w] = E0 + E1;
    __syncthreads();

    // prefetch next decoder row; poll stall below hides the latency
    f32x4 dvn[3];
    if (t + 1 < NSTEP) {
      const float* drn = decf + (size_t)(b * Tq + t + 1) * Hq;
#pragma unroll
      for (int jj = 0; jj < 3; jj++) dvn[jj] = *(const f32x4*)(drn + hb + 256 * jj);
    }

    const int base = (b * NSTEP + t) * GPB;
    if (w == 0) {
      float p = (ln < 8) ? zsum[par][ln] : 0.f;
      p += __shfl_xor(p, 1); p += __shfl_xor(p, 2); p += __shfl_xor(p, 4);
      if (ln == 0)
        __hip_atomic_store(&Zpart[base + g], p, __ATOMIC_RELAXED, __HIP_MEMORY_SCOPE_AGENT);
    }
    // every wave polls all 16 slots (one cache line) and reduces Z itself
    unsigned u;
    do {
      u = __hip_atomic_load(&Zp[base + (ln & 15)], __ATOMIC_RELAXED, __HIP_MEMORY_SCOPE_AGENT);
    } while (__ballot(u == POISON));
    float zf = __uint_as_float(u);
    zf += __shfl_xor(zf, 1); zf += __shfl_xor(zf, 2);
    zf += __shfl_xor(zf, 4); zf += __shfl_xor(zf, 8);

    const float invZ = __builtin_amdgcn_rcpf(zf);
    float at0 = E0 * invZ, at1 = E1 * invZ;
    cva += at0; cvb += at1;
    if (ln == 0) {
      out_attn[(size_t)(b * Tq + t) * Sq + s0] = at0;
      out_attn[(size_t)(b * Tq + t) * Sq + s1] = at1;
    }
#pragma unroll
    for (int jj = 0; jj < 3; jj++) dv[jj] = dvn[jj];
  }
}

// ---------------- deferred ht = attn @ enc (fp32 VALU) -----------------------
// grid 192: (b, tc of 8 t-rows, hc of 256 h-cols). 256 threads.
__global__ __launch_bounds__(256) void ht_kernel(
    const float* __restrict__ attn, const float* __restrict__ enc,
    float* __restrict__ out_ht)
{
  __shared__ float lat[8][Sq];
  int bid = blockIdx.x;
  int b = bid / 24, r = bid % 24, tc = r / 3, hc = r % 3;
  int tid = threadIdx.x;
  int h = hc * 256 + tid;
#pragma unroll
  for (int tt = 0; tt < 8; tt++)
    lat[tt][tid] = attn[(size_t)(b * Tq + tc * 8 + tt) * Sq + tid];
  __syncthreads();
  float acc[8] = {};
  for (int s = 0; s < Sq; s++) {
    float e = enc[(size_t)(b * Sq + s) * Hq + h];
#pragma unroll
    for (int tt = 0; tt < 8; tt++) acc[tt] += lat[tt][s] * e;
  }
#pragma unroll
  for (int tt = 0; tt < 8; tt++)
    out_ht[(size_t)(b * Tq + tc * 8 + tt) * Hq + h] = acc[tt];
}

// ---------------- deferred coverage cumsum + loss + coverage_final -----------
// 8 blocks (one per batch) x 256 threads (one per s).
__global__ __launch_bounds__(256) void loss_kernel(
    const float* __restrict__ attn, const float* __restrict__ cov0,
    const float* __restrict__ dmask,
    float* __restrict__ out_covf, float* __restrict__ loss_acc)
{
  __shared__ float red[256];
  int b = blockIdx.x, s = threadIdx.x;
  float cov = cov0[b * Sq + s];
  float lp = 0.f;
  for (int t = 0; t < Tq; t++) {
    float a = attn[(size_t)(b * Tq + t) * Sq + s];
    lp += fminf(a, cov) * dmask[b * Tq + t];
    cov += a;
  }
  out_covf[b * Sq + s] = cov;
  red[s] = lp;
  __syncthreads();
  if (s < 64) {
    float v = red[s] + red[s + 64] + red[s + 128] + red[s + 192];
#pragma unroll
    for (int off = 32; off; off >>= 1) v += __shfl_xor(v, off);
    if (s == 0) atomicAdd(loss_acc, v);
  }
}

// ---------------- finalize loss ----------------------------------------------
__global__ __launch_bounds__(256) void finalize_kernel(
    const float* __restrict__ dmask, const float* __restrict__ loss_acc,
    float* __restrict__ out_loss)
{
  __shared__ float red[256];
  float s = 0.f;
  for (int i = threadIdx.x; i < Bq * Tq; i += 256) s += dmask[i];
  red[threadIdx.x] = s;
  __syncthreads();
  if (threadIdx.x == 0) {
    float tot = 0.f;
    for (int i = 0; i < 256; i++) tot += red[i];
    out_loss[0] = loss_acc[0] / tot;
  }
}

extern "C" void kernel_launch(void* const* d_in, const int* in_sizes, int n_in,
                              void* d_out, int out_size, void* d_ws, size_t ws_size,
                              hipStream_t stream) {
  const float* dec   = (const float*)d_in[0];   // [8,64,768]
  const float* dmask = (const float*)d_in[1];   // [8,64]
  const float* enc   = (const float*)d_in[2];   // [8,256,768]
  const float* emask = (const float*)d_in[3];   // [8,256]
  const float* cov0  = (const float*)d_in[4];   // [8,256]
  const float* Wh    = (const float*)d_in[5];   // [768,768]
  const float* Wd    = (const float*)d_in[6];   // [768,768]
  const float* bd    = (const float*)d_in[7];   // [768]
  const float* wc    = (const float*)d_in[8];   // [768]
  const float* vv    = (const float*)d_in[9];   // [768]
  float* out = (float*)d_out;

  char* ws = (char*)d_ws;
  float* ef    = (float*)ws;                     // 2048*768 f32 = 6291456 B
  float* decf  = (float*)(ws + 6291456);         // 512*768 f32 = 1572864 B
  float* Zpart = (float*)(ws + 7864320);         // 8*64*16 f32 = 32768 B
  float* lacc  = (float*)(ws + 7897088);         // 1 f32

  const size_t OFF_ATTN = (size_t)Bq * Tq * Hq;             // 393216
  const size_t OFF_LOSS = OFF_ATTN + (size_t)Bq * Tq * Sq;  // 524288
  const size_t OFF_COV  = OFF_LOSS + 1;                     // 524289

  hipMemsetAsync(ws + 7864320, 0xFF, 32768, stream);  // poison Z slots
  hipMemsetAsync(ws + 7897088, 0, 4, stream);         // zero loss accumulator

  proj_kernel<<<480, 256, 0, stream>>>(enc, dec, Wh, Wd, bd, ef, decf);
  scan_kernel<<<Bq * GPB, 512, 0, stream>>>(ef, decf, emask, cov0, vv, wc,
                                            out + OFF_ATTN, Zpart);
  ht_kernel<<<192, 256, 0, stream>>>(out + OFF_ATTN, enc, out);
  loss_kernel<<<Bq, 256, 0, stream>>>(out + OFF_ATTN, cov0, dmask,
                                      out + OFF_COV, lacc);
  finalize_kernel<<<1, 256, 0, stream>>>(dmask, lacc, out + OFF_LOSS);
}

// Round 3
// 229.202 us; speedup vs baseline: 2.7096x; 1.1794x over previous
//
#include <hip/hip_runtime.h>

#define Bq 8
#define Tq 64
#define Sq 256
#define Hq 768
#define GPB 16          // workgroups per batch (scan)
#define NSTEP 64

typedef float f32x4 __attribute__((ext_vector_type(4)));
typedef __bf16 bf16x8 __attribute__((ext_vector_type(8)));

#define TANH_SCALE 2.885390081777927f   // 2*log2(e)
#define LOG2E 1.4426950408889634f
#define POISON 0xFFFFFFFFu

// ---------------- projection GEMMs (bf16 MFMA, direct-from-global frags) -----
__global__ __launch_bounds__(256) void proj_kernel(
    const float* __restrict__ enc, const float* __restrict__ dec,
    const float* __restrict__ Wh, const float* __restrict__ Wd,
    const float* __restrict__ bd,
    float* __restrict__ ef, float* __restrict__ decf)
{
  const int NT = Hq / 64;                       // 12 n-tiles
  int bid = blockIdx.x;
  const int efBlocks = (Bq * Sq / 64) * NT;     // 384
  const float* A; const float* W; float* C; bool hasBias;
  if (bid < efBlocks) { A = enc; W = Wh; C = ef; hasBias = false; }
  else { bid -= efBlocks; A = dec; W = Wd; C = decf; hasBias = true; }
  int bm = bid / NT, bn = bid % NT;
  int w = threadIdx.x >> 6, ln = threadIdx.x & 63;
  int m0 = bm * 64 + (w >> 1) * 32;
  int n0 = bn * 64 + (w & 1) * 32;
  int rsel = ln & 15;
  int kof = (ln >> 4) * 8;
  f32x4 acc[2][2] = {};
  for (int k0 = 0; k0 < Hq; k0 += 32) {
    bf16x8 af[2], bfr[2];
#pragma unroll
    for (int tm = 0; tm < 2; tm++) {
      const float* p = A + (size_t)(m0 + tm * 16 + rsel) * Hq + k0 + kof;
      f32x4 lo = *(const f32x4*)p, hi = *(const f32x4*)(p + 4);
      bf16x8 t;
      t[0] = (__bf16)lo[0]; t[1] = (__bf16)lo[1]; t[2] = (__bf16)lo[2]; t[3] = (__bf16)lo[3];
      t[4] = (__bf16)hi[0]; t[5] = (__bf16)hi[1]; t[6] = (__bf16)hi[2]; t[7] = (__bf16)hi[3];
      af[tm] = t;
    }
#pragma unroll
    for (int tn = 0; tn < 2; tn++) {
      const float* p = W + (size_t)(n0 + tn * 16 + rsel) * Hq + k0 + kof;
      f32x4 lo = *(const f32x4*)p, hi = *(const f32x4*)(p + 4);
      bf16x8 t;
      t[0] = (__bf16)lo[0]; t[1] = (__bf16)lo[1]; t[2] = (__bf16)lo[2]; t[3] = (__bf16)lo[3];
      t[4] = (__bf16)hi[0]; t[5] = (__bf16)hi[1]; t[6] = (__bf16)hi[2]; t[7] = (__bf16)hi[3];
      bfr[tn] = t;
    }
#pragma unroll
    for (int tm = 0; tm < 2; tm++)
#pragma unroll
      for (int tn = 0; tn < 2; tn++)
        acc[tm][tn] = __builtin_amdgcn_mfma_f32_16x16x32_bf16(af[tm], bfr[tn], acc[tm][tn], 0, 0, 0);
  }
  int col = ln & 15, rb = (ln >> 4) * 4;
#pragma unroll
  for (int tm = 0; tm < 2; tm++)
#pragma unroll
    for (int tn = 0; tn < 2; tn++)
#pragma unroll
      for (int j = 0; j < 4; j++) {
        int r = m0 + tm * 16 + rb + j, c = n0 + tn * 16 + col;
        float val = acc[tm][tn][j];
        if (hasBias) val += bd[c];
        C[(size_t)r * Hq + c] = val * TANH_SCALE;
      }
}

// ---------------- persistent scan kernel -------------------------------------
// 128 blocks x 512 threads. b = bid&7 (XCD-aligned), g = bid>>3.
// Block (b,g) owns rows s = g*16 .. g*16+15; wave w owns s0=g*16+2w, s1=s0+1.
// Per step only scalar Z crosses WGs. Wave 0 is the sole poller per WG;
// other waves prefetch and wait at the barrier (kills LLC poll contention).
__global__ __launch_bounds__(512, 1) void scan_kernel(
    const float* __restrict__ ef, const float* __restrict__ decf,
    const float* __restrict__ emask, const float* __restrict__ cov0,
    const float* __restrict__ vvec, const float* __restrict__ wcvec,
    const float* __restrict__ dmask,
    float* __restrict__ out_attn, float* __restrict__ out_covf,
    float* __restrict__ Zpart, float* __restrict__ lacc)
{
  __shared__ float zsum[2][8];
  __shared__ float zshs[2];
  __shared__ float lossb[8];
  const int b = blockIdx.x & 7;          // batch <-> XCD
  const int g = blockIdx.x >> 3;
  const int w = threadIdx.x >> 6;
  const int ln = threadIdx.x & 63;
  const int s0 = g * 16 + w * 2, s1 = s0 + 1;
  const int hb = 4 * ln;

  f32x4 vv[3], wcv[3], ef0[3], ef1[3];
  const float* efr0 = ef + (size_t)(b * Sq + s0) * Hq;
  const float* efr1 = ef + (size_t)(b * Sq + s1) * Hq;
#pragma unroll
  for (int jj = 0; jj < 3; jj++) {
    int o = hb + 256 * jj;
    vv[jj]  = *(const f32x4*)(vvec + o);
    f32x4 wcl = *(const f32x4*)(wcvec + o);
    wcv[jj] = wcl * TANH_SCALE;
    ef0[jj] = *(const f32x4*)(efr0 + o);
    ef1[jj] = *(const f32x4*)(efr1 + o);
  }
  float cva = cov0[b * Sq + s0], cvb = cov0[b * Sq + s1];
  const float em0 = emask[b * Sq + s0], em1 = emask[b * Sq + s1];
  float lp = 0.f;

  unsigned* Zp = (unsigned*)Zpart;

  f32x4 dv[3];
#pragma unroll
  for (int jj = 0; jj < 3; jj++)
    dv[jj] = *(const f32x4*)(decf + (size_t)(b * Tq) * Hq + hb + 256 * jj);

  for (int t = 0; t < NSTEP; t++) {
    const int par = t & 1;
    const float dmt = dmask[b * Tq + t];
    float acc0 = 0.f, acc1 = 0.f;
#pragma unroll
    for (int jj = 0; jj < 3; jj++)
#pragma unroll
      for (int e = 0; e < 4; e++) {
        float d = dv[jj][e], wcx = wcv[jj][e], vx = vv[jj][e];
        float xa = ef0[jj][e] + d + cva * wcx;    // pre-scaled by 2*log2(e)
        float xb = ef1[jj][e] + d + cvb * wcx;
        float ta = 1.f - 2.f * __builtin_amdgcn_rcpf(1.f + __builtin_amdgcn_exp2f(xa));
        float tb = 1.f - 2.f * __builtin_amdgcn_rcpf(1.f + __builtin_amdgcn_exp2f(xb));
        acc0 += vx * ta;
        acc1 += vx * tb;
      }
#pragma unroll
    for (int off = 32; off; off >>= 1) {
      acc0 += __shfl_xor(acc0, off);
      acc1 += __shfl_xor(acc1, off);
    }
    float E0 = __builtin_amdgcn_exp2f(acc0 * LOG2E) * em0;
    float E1 = __builtin_amdgcn_exp2f(acc1 * LOG2E) * em1;
    if (ln == 0) zsum[par][w] = E0 + E1;
    __syncthreads();

    // all waves issue next decf prefetch (in flight during the Z exchange)
    f32x4 dvn[3];
    if (t + 1 < NSTEP) {
      const float* drn = decf + (size_t)(b * Tq + t + 1) * Hq;
#pragma unroll
      for (int jj = 0; jj < 3; jj++) dvn[jj] = *(const f32x4*)(drn + hb + 256 * jj);
    }

    const int base = (b * NSTEP + t) * GPB;
    if (w == 0) {
      float p = (ln < 8) ? zsum[par][ln] : 0.f;
      p += __shfl_xor(p, 1); p += __shfl_xor(p, 2); p += __shfl_xor(p, 4);
      if (ln == 0)
        __hip_atomic_store(&Zpart[base + g], p, __ATOMIC_RELAXED, __HIP_MEMORY_SCOPE_AGENT);
      unsigned u;
      do {
        u = __hip_atomic_load(&Zp[base + (ln & 15)], __ATOMIC_RELAXED, __HIP_MEMORY_SCOPE_AGENT);
      } while (__ballot(u == POISON));
      float zf = __uint_as_float(u);
      zf += __shfl_xor(zf, 1); zf += __shfl_xor(zf, 2);
      zf += __shfl_xor(zf, 4); zf += __shfl_xor(zf, 8);
      if (ln == 0) zshs[par] = zf;
    }
    __syncthreads();

    const float invZ = __builtin_amdgcn_rcpf(zshs[par]);
    float at0 = E0 * invZ, at1 = E1 * invZ;
    lp += (fminf(at0, cva) + fminf(at1, cvb)) * dmt;
    cva += at0; cvb += at1;
    if (ln == 0) {
      out_attn[(size_t)(b * Tq + t) * Sq + s0] = at0;
      out_attn[(size_t)(b * Tq + t) * Sq + s1] = at1;
    }
#pragma unroll
    for (int jj = 0; jj < 3; jj++) dv[jj] = dvn[jj];
  }

  if (ln == 0) {
    out_covf[b * Sq + s0] = cva;
    out_covf[b * Sq + s1] = cvb;
    lossb[w] = lp;
  }
  __syncthreads();
  if (w == 0) {
    float p = (ln < 8) ? lossb[ln] : 0.f;
    p += __shfl_xor(p, 1); p += __shfl_xor(p, 2); p += __shfl_xor(p, 4);
    if (ln == 0) atomicAdd(lacc, p);
  }
}

// ---------------- deferred ht = attn @ enc (fp32 VALU) + loss finalize -------
// grid 384: (b, tc of 4 t-rows(16), hc of 256 h-cols(3)). 256 threads.
__global__ __launch_bounds__(256) void ht_kernel(
    const float* __restrict__ attn, const float* __restrict__ enc,
    const float* __restrict__ dmask, const float* __restrict__ lacc,
    float* __restrict__ out_ht, float* __restrict__ out_loss)
{
  __shared__ float lat[4][Sq];
  __shared__ float r4[4];
  int bid = blockIdx.x;
  int b = bid / 48, r = bid % 48, tc = r / 3, hc = r % 3;
  int tid = threadIdx.x;
  int h = hc * 256 + tid;
#pragma unroll
  for (int tt = 0; tt < 4; tt++)
    lat[tt][tid] = attn[(size_t)(b * Tq + tc * 4 + tt) * Sq + tid];
  __syncthreads();
  float acc[4] = {};
  for (int s = 0; s < Sq; s++) {
    float e = enc[(size_t)(b * Sq + s) * Hq + h];
#pragma unroll
    for (int tt = 0; tt < 4; tt++) acc[tt] += lat[tt][s] * e;
  }
#pragma unroll
  for (int tt = 0; tt < 4; tt++)
    out_ht[(size_t)(b * Tq + tc * 4 + tt) * Hq + h] = acc[tt];

  if (blockIdx.x == 0) {
    // finalize converge_loss = lacc / sum(dmask)
    float s = 0.f;
    for (int i = tid; i < Bq * Tq; i += 256) s += dmask[i];
#pragma unroll
    for (int off = 32; off; off >>= 1) s += __shfl_xor(s, off);
    int w = tid >> 6, ln = tid & 63;
    if (ln == 0) r4[w] = s;
    __syncthreads();
    if (tid == 0) out_loss[0] = lacc[0] / (r4[0] + r4[1] + r4[2] + r4[3]);
  }
}

extern "C" void kernel_launch(void* const* d_in, const int* in_sizes, int n_in,
                              void* d_out, int out_size, void* d_ws, size_t ws_size,
                              hipStream_t stream) {
  const float* dec   = (const float*)d_in[0];   // [8,64,768]
  const float* dmask = (const float*)d_in[1];   // [8,64]
  const float* enc   = (const float*)d_in[2];   // [8,256,768]
  const float* emask = (const float*)d_in[3];   // [8,256]
  const float* cov0  = (const float*)d_in[4];   // [8,256]
  const float* Wh    = (const float*)d_in[5];   // [768,768]
  const float* Wd    = (const float*)d_in[6];   // [768,768]
  const float* bd    = (const float*)d_in[7];   // [768]
  const float* wc    = (const float*)d_in[8];   // [768]
  const float* vv    = (const float*)d_in[9];   // [768]
  float* out = (float*)d_out;

  char* ws = (char*)d_ws;
  float* ef    = (float*)ws;                     // 2048*768 f32 = 6291456 B
  float* decf  = (float*)(ws + 6291456);         // 512*768 f32 = 1572864 B
  float* Zpart = (float*)(ws + 7864320);         // 8*64*16 f32 = 32768 B
  float* lacc  = (float*)(ws + 7897088);         // 1 f32

  const size_t OFF_ATTN = (size_t)Bq * Tq * Hq;             // 393216
  const size_t OFF_LOSS = OFF_ATTN + (size_t)Bq * Tq * Sq;  // 524288
  const size_t OFF_COV  = OFF_LOSS + 1;                     // 524289

  hipMemsetAsync(ws + 7864320, 0xFF, 32768, stream);  // poison Z slots
  hipMemsetAsync(ws + 7897088, 0, 4, stream);         // zero loss accumulator

  proj_kernel<<<480, 256, 0, stream>>>(enc, dec, Wh, Wd, bd, ef, decf);
  scan_kernel<<<Bq * GPB, 512, 0, stream>>>(ef, decf, emask, cov0, vv, wc,
                                            dmask, out + OFF_ATTN,
                                            out + OFF_COV, Zpart, lacc);
  ht_kernel<<<384, 256, 0, stream>>>(out + OFF_ATTN, enc, dmask, lacc,
                                     out, out + OFF_LOSS);
}